// Round 5
// baseline (128.586 us; speedup 1.0000x reference)
//
#include <hip/hip_runtime.h>

// RecursiveNN: 11-level binary tree, shared linear map W(128x256)+b, bf16 MFMA.
// Round-4 post-mortem: 4 blocks/CU (occupancy 27->35%) left dur EXACTLY at
// 49.5us, and round-3 L3-warm replays ran the same time at 2.3MB traffic.
// => phase-serialization-bound: gather (HBM, ~20us) and levels (MFMA ~21us +
// LDS ~8us) are additive because all blocks run in near-lockstep.
// Fix: intra-block software pipelining (T14). 2 groups/block (2048 blocks),
// third 64-row LDS buffer C as the next-h1 landing zone:
//   - h2 loads issued BEFORE L1h1, drained at L1h1's end-barrier (compiler
//     emits vmcnt(0) before s_barrier - the drain IS the wait we want).
//   - next group's h1 loads issued before L2, land in C (dead there).
// Only the prologue h1 (32KB/block) stays exposed; ~3/4 of gather hidden.
// Regs: h2-staging and h1'-staging are disjoint by construction; peak ~92
// arch + 64 wf = ~156 <= 170 budget at launch_bounds(256,3). LDS 3x17408 =
// 52224 B -> 3 blocks/CU (156.7 <= 160 KB). 4/CU proven worthless (round 4).
// STRIDE=136 padded rows: 0 conflicts measured. Spill tripwire: WRITE_SIZE.

typedef __bf16 bf16x8 __attribute__((ext_vector_type(8)));
typedef __bf16 bf16x4 __attribute__((ext_vector_type(4)));
typedef float f32x4 __attribute__((ext_vector_type(4)));

#define STRIDE 136  // 128 cols + 8 pad bf16 = 272B rows; 0 LDS conflicts measured

// Pack W (fp32 128x256) into MFMA B-fragment lane order (bf16):
//   frag f=nl*8+kk, wave wv, lane l: elem j = W[o][d+j],
//   o=(2wv+nl)*16+(l&15), d=kk*32+(l>>4)*8; stored at wpack[(f*256+tid)*8].
__global__ void pack_w_kernel(const float* __restrict__ W,
                              __bf16* __restrict__ wpack) {
    const int f = blockIdx.x;
    const int tid = threadIdx.x;
    const int wv = tid >> 6, l = tid & 63;
    const int nl = f >> 3, kk = f & 7;
    const int o = ((wv << 1) + nl) * 16 + (l & 15);
    const int d = kk * 32 + ((l >> 4) << 3);
    const float* src = W + o * 256 + d;
    bf16x8 h;
#pragma unroll
    for (int j = 0; j < 8; ++j) h[j] = (__bf16)src[j];
    *(bf16x8*)(wpack + (size_t)(f * 256 + tid) * 8) = h;
}

// One level-step: NOUT local outputs from 2*NOUT local input rows.
// src0 = rows 0..31, src1 = rows 32..63 (unused when NOUT<=16). Ends in barrier.
// K split into two halves (af[4] live at a time); per-acc K-accumulation order
// kk=0..7 preserved (bit-identical numerics to the verified round-0 kernel).
template <int NOUT>
__device__ __forceinline__ void level_step(
    const __bf16* src0, const __bf16* src1, __bf16* dst,
    const bf16x8* wf, const float* bval, int wv, int q, int lm)
{
    const int ntm = (NOUT + 15) >> 4;
#pragma unroll
    for (int mt = 0; mt < ntm; ++mt) {
        const __bf16* src = mt ? src1 : src0;
        // clamp: padded lanes broadcast row 0/1 (free; no garbage traffic)
        const int me = (NOUT >= 16) ? lm : (lm < NOUT ? lm : 0);
        f32x4 acc[2];
        acc[0] = f32x4{ bval[0], bval[0], bval[0], bval[0] };
        acc[1] = f32x4{ bval[1], bval[1], bval[1], bval[1] };
#pragma unroll
        for (int kh = 0; kh < 2; ++kh) {        // K half: rows 2me / 2me+1
            const int row = 2 * me + kh;
            bf16x8 af[4];
#pragma unroll
            for (int j = 0; j < 4; ++j)
                af[j] = *(const bf16x8*)&src[row * STRIDE + j * 32 + q * 8];
#pragma unroll
            for (int nl = 0; nl < 2; ++nl)
#pragma unroll
                for (int j = 0; j < 4; ++j)
                    acc[nl] = __builtin_amdgcn_mfma_f32_16x16x32_bf16(
                        af[j], wf[nl * 8 + kh * 4 + j], acc[nl], 0, 0, 0);
        }
#pragma unroll
        for (int nl = 0; nl < 2; ++nl) {
            const int col = (2 * wv + nl) * 16 + lm;  // D col = lane&15
            const bf16x4 hv = __builtin_convertvector(acc[nl], bf16x4);
#pragma unroll
            for (int r = 0; r < 4; ++r) {
                const int row = mt * 16 + q * 4 + r;  // D row
                if (row < NOUT)
                    dst[row * STRIDE + col] = hv[r];
            }
        }
    }
    __syncthreads();
}

// 4 input rows -> 2 subtree roots straight to global (bf16). No barrier.
__device__ __forceinline__ void level_final(
    const __bf16* src, __bf16* yrow,
    const bf16x8* wf, const float* bval, int wv, int q, int lm)
{
    const int me = (lm < 2) ? lm : 0;
    f32x4 acc[2];
    acc[0] = f32x4{ bval[0], bval[0], bval[0], bval[0] };
    acc[1] = f32x4{ bval[1], bval[1], bval[1], bval[1] };
#pragma unroll
    for (int kh = 0; kh < 2; ++kh) {
        const int row = 2 * me + kh;
        bf16x8 af[4];
#pragma unroll
        for (int j = 0; j < 4; ++j)
            af[j] = *(const bf16x8*)&src[row * STRIDE + j * 32 + q * 8];
#pragma unroll
        for (int nl = 0; nl < 2; ++nl)
#pragma unroll
            for (int j = 0; j < 4; ++j)
                acc[nl] = __builtin_amdgcn_mfma_f32_16x16x32_bf16(
                    af[j], wf[nl * 8 + kh * 4 + j], acc[nl], 0, 0, 0);
    }
#pragma unroll
    for (int nl = 0; nl < 2; ++nl) {
        const int col = (2 * wv + nl) * 16 + lm;
        if (q == 0) {                 // rows 0,1 = quad 0 regs 0,1
            yrow[0 * 128 + col] = (__bf16)acc[nl][0];
            yrow[1 * 128 + col] = (__bf16)acc[nl][1];
        }
    }
}

// Issue 64-row gather (ids wb64[0..63]) into 32 staging VGPRs. No wait here:
// the consumer (gather_write) triggers the compiler's s_waitcnt, and any
// intervening level_step barrier drains vmcnt - that drain is the overlap.
__device__ __forceinline__ void gather_issue(
    const int* wb64, const float* emb, int tid, f32x4 (&s)[8])
{
#pragma unroll
    for (int i = 0; i < 8; ++i) {
        const int id = wb64[(tid >> 5) + 8 * i];
        s[i] = *(const f32x4*)(emb + (size_t)id * 128 + (tid & 31) * 4);
    }
}

// Convert staged fp32 rows -> bf16 LDS rows 0..63 (coalesced 512B per row-group).
__device__ __forceinline__ void gather_write(
    __bf16* dst, int tid, const f32x4 (&s)[8])
{
#pragma unroll
    for (int i = 0; i < 8; ++i) {
        const int row = (tid >> 5) + 8 * i;
        *(bf16x4*)&dst[row * STRIDE + (tid & 31) * 4] =
            __builtin_convertvector(s[i], bf16x4);
    }
}

// Kernel 1: one block = 2 groups x 128 leaves (2048 blocks). Per group g:
//   L1h1: C(h1) -> B[0:31]      (h2 loads in flight underneath)
//   write h2 -> A; barrier
//   L1h2: A -> B[32:63]
//   [g==0: issue next h1]       (lands under L2)
//   L2:  B[0:63] -> A[0:31]
//   [g==0: write next h1 -> C]  (C dead since this group's L1h1)
//   L3:  A[0:31] -> B[0:15]     L4: B[0:15] -> A[0:7]
//   L5:  A[0:7]  -> B[0:3]      final: B[0:3] -> global roots
//   barrier (protects B[0:3] before next L1h1 writes B[0:31])
// Staging-reg liveness: h2 (steps 1-2) and next-h1 (steps 4-5) are disjoint.
__global__ __launch_bounds__(256, 3) void tree128_kernel(
    const int* __restrict__ wid, const float* __restrict__ emb,
    const __bf16* __restrict__ wpack, const float* __restrict__ bias,
    __bf16* __restrict__ yout)
{
    __shared__ __align__(16) __bf16 bufA[64 * STRIDE];  // 17408 B
    __shared__ __align__(16) __bf16 bufB[64 * STRIDE];  // 17408 B
    __shared__ __align__(16) __bf16 bufC[64 * STRIDE];  // 17408 B -> 52224 total
    const int tid = threadIdx.x;
    const int batch = blockIdx.x >> 3;   // 8 group-pairs per batch
    const int pair = blockIdx.x & 7;
    const int wv = tid >> 6, ln = tid & 63, q = ln >> 4, lm = ln & 15;

    // W fragments: 16 x (8 bf16) = 64 regs (AGPR-resident), coalesced 256B/thread.
    bf16x8 wf[16];
    const bf16x8* wp = (const bf16x8*)wpack;
#pragma unroll
    for (int f = 0; f < 16; ++f) wf[f] = wp[f * 256 + tid];
    float bval[2];
    bval[0] = bias[(2 * wv + 0) * 16 + lm];
    bval[1] = bias[(2 * wv + 1) * 16 + lm];

    const int* wb = wid + batch * 2048 + pair * 256;  // 256 leaves for this block
    f32x4 st[8];                                      // 32 staging VGPRs (shared)

    // Prologue: group 0 h1 -> C (the only exposed gather).
    gather_issue(wb, emb, tid, st);
    gather_write(bufC, tid, st);
    __syncthreads();

#pragma unroll
    for (int g = 0; g < 2; ++g) {
        const int* wg = wb + g * 128;
        // h2 loads fly under L1h1; drained at its end-barrier.
        gather_issue(wg + 64, emb, tid, st);
        level_step<32>(bufC, bufC + 32 * STRIDE, bufB, wf, bval, wv, q, lm);
        gather_write(bufA, tid, st);      // A free: L5(g-1) consumed A[0:7]
        __syncthreads();
        level_step<32>(bufA, bufA + 32 * STRIDE, bufB + 32 * STRIDE,
                       wf, bval, wv, q, lm);
        if (g == 0)                        // next-h1 loads fly under L2
            gather_issue(wb + 128, emb, tid, st);
        level_step<32>(bufB, bufB + 32 * STRIDE, bufA, wf, bval, wv, q, lm);
        if (g == 0)
            gather_write(bufC, tid, st);   // C dead since this group's L1h1
        level_step<16>(bufA, nullptr, bufB, wf, bval, wv, q, lm);
        level_step<8> (bufB, nullptr, bufA, wf, bval, wv, q, lm);
        level_step<4> (bufA, nullptr, bufB, wf, bval, wv, q, lm);
        level_final(bufB, yout + (size_t)(batch * 32 + (pair * 2 + g) * 2) * 128,
                    wf, bval, wv, q, lm);
        __syncthreads();                   // B[0:3] read before next L1h1 writes B
    }
}

// Kernel 2: one block = one batch; 32 subtree roots -> 5 levels -> fp32 row.
__global__ __launch_bounds__(256) void tree32_kernel(
    const __bf16* __restrict__ yin, const __bf16* __restrict__ wpack,
    const float* __restrict__ bias, float* __restrict__ out)
{
    __shared__ __align__(16) __bf16 buf0[32 * STRIDE];  // 8704 B
    __shared__ __align__(16) __bf16 buf1[16 * STRIDE];  // 4352 B
    const int tid = threadIdx.x;
    const int batch = blockIdx.x;
    const int wv = tid >> 6, ln = tid & 63, q = ln >> 4, lm = ln & 15;

    bf16x8 wf[16];
    const bf16x8* wp = (const bf16x8*)wpack;
#pragma unroll
    for (int f = 0; f < 16; ++f) wf[f] = wp[f * 256 + tid];
    float bval[2];
    bval[0] = bias[(2 * wv + 0) * 16 + lm];
    bval[1] = bias[(2 * wv + 1) * 16 + lm];

#pragma unroll
    for (int i = 0; i < 2; ++i) {
        const int flat = tid + 256 * i;
        const int row = flat >> 4;
        const int c8 = flat & 15;
        const bf16x8 v =
            *(const bf16x8*)(yin + (size_t)(batch * 32 + row) * 128 + c8 * 8);
        *(bf16x8*)&buf0[row * STRIDE + c8 * 8] = v;
    }
    __syncthreads();

    level_step<16>(buf0, nullptr, buf1, wf, bval, wv, q, lm);  // 32->16
    level_step<8> (buf1, nullptr, buf0, wf, bval, wv, q, lm);  // 16->8
    level_step<4> (buf0, nullptr, buf1, wf, bval, wv, q, lm);  // 8->4
    level_step<2> (buf1, nullptr, buf0, wf, bval, wv, q, lm);  // 4->2

    // Final: rows 0,1 of buf0 -> root row (fp32 out).
    {
        f32x4 acc[2];
        acc[0] = f32x4{ bval[0], bval[0], bval[0], bval[0] };
        acc[1] = f32x4{ bval[1], bval[1], bval[1], bval[1] };
#pragma unroll
        for (int kh = 0; kh < 2; ++kh) {
            bf16x8 af[4];
#pragma unroll
            for (int j = 0; j < 4; ++j)
                af[j] = *(const bf16x8*)&buf0[kh * STRIDE + j * 32 + q * 8];
#pragma unroll
            for (int nl = 0; nl < 2; ++nl)
#pragma unroll
                for (int j = 0; j < 4; ++j)
                    acc[nl] = __builtin_amdgcn_mfma_f32_16x16x32_bf16(
                        af[j], wf[nl * 8 + kh * 4 + j], acc[nl], 0, 0, 0);
        }
#pragma unroll
        for (int nl = 0; nl < 2; ++nl) {
            const int col = (2 * wv + nl) * 16 + lm;
            if (q == 0) out[(size_t)batch * 128 + col] = acc[nl][0];
        }
    }
}

extern "C" void kernel_launch(void* const* d_in, const int* in_sizes, int n_in,
                              void* d_out, int out_size, void* d_ws, size_t ws_size,
                              hipStream_t stream) {
    const int*   wid = (const int*)d_in[0];      // (256, 2048) int32
    const float* emb = (const float*)d_in[1];    // (100000, 128) fp32
    const float* W   = (const float*)d_in[2];    // (128, 256) fp32
    const float* b   = (const float*)d_in[3];    // (128,) fp32
    float* out = (float*)d_out;                  // (256, 128) fp32

    __bf16* wpack = (__bf16*)d_ws;               // 32768 elems = 64 KB
    __bf16* y     = wpack + 32768;               // (256,32,128) bf16 = 2 MB

    pack_w_kernel<<<16, 256, 0, stream>>>(W, wpack);
    tree128_kernel<<<2048, 256, 0, stream>>>(wid, emb, wpack, b, y);
    tree32_kernel<<<256, 256, 0, stream>>>(y, wpack, b, out);
}